// Round 1
// baseline (133.508 us; speedup 1.0000x reference)
//
#include <hip/hip_runtime.h>

// MACD on [B=512, T=16384] fp32 — partial-fraction / rolling-chunk version.
//
// Round-2 change vs the 3-phase version: the cascade
//   signal = EMA_g(EMA_s(x) - EMA_l(x))
// is a composition of one-pole filters with distinct poles, so it partial-
// fraction-decomposes into a combination of THREE INDEPENDENT EMAs of x:
//   S = EMA_{b_s}(x), L = EMA_{b_l}(x), G = EMA_{b_g}(x)
//   macd   = S - L
//   signal = c_s*S + c_l*L + c_g*G        (c_s+c_l+c_g = 0)
//   hist   = macd - signal
// with c_s = a_g*b_s/(b_s-b_g), c_l = -a_g*b_l/(b_l-b_g),
//      c_g = b_g*(a_s/(b_g-b_s) - a_l/(b_g-b_l)).
// The x0-prefix init carries over: on the constant-x0 warm-up prefix
// S=L=G=x0, so signal_0 = 0 = reference init, exactly as before.
//
// This removes the short/long->macd->signal dependency, so the kernel is ONE
// rolling loop over 5 chunks with only 3 scalar carries (zero-carry chunk
// totals, b^256-truncated chain). Peak register liveness collapses from
// ~170 VGPRs (3-phase version: all ls/ll/m/lg arrays live across phases,
// spilling ~40 regs past the 128 cap) to ~60-90 -> no scratch traffic.
//
// Numerics (threshold 1.87e-2, previous absmax 3.9e-3):
//   wave-scan truncation: short 4 steps (drops b_s^64=2.3e-5), long 5 steps
//   (drops b_l^128=5.3e-5), signal-pole 4 steps (drops b_g^64=6.3e-7).
//   Coefficient amplification of truncation errors <= ~2e-4. Cross-chunk
//   b^256 attenuation <= 2.8e-9.

constexpr int kB = 512;
constexpr int kT = 16384;
constexpr int kSeg = 1024;                 // outputs per wave
constexpr int kChunk = 256;                // 64 lanes * 4
constexpr int kChunks = 5;                 // 1 warm-up + 4 output chunks
constexpr int kSegsPerRow = kT / kSeg;     // 16
constexpr int kWPB = 4;                    // waves per block (256 threads)

// Inclusive wave scan over lane aggregates (multiplier m0 = b^4 per lane
// step), truncated to STEPS steps. Returns exclusive prefix (carry into this
// lane) and the chunk total (lane 63 inclusive), both zero-carry.
template <int STEPS>
__device__ __forceinline__ void wave_scan(float agg, float m0, int lane,
                                          float& ex, float& tot) {
  float m = m0, z = agg;
#pragma unroll
  for (int i = 0; i < STEPS; ++i) {
    const int d = 1 << i;
    float t = __shfl_up(z, d, 64);
    if (lane >= d) z = fmaf(m, t, z);
    m = m * m;
  }
  ex = __shfl_up(z, 1, 64);
  if (lane == 0) ex = 0.0f;
  tot = __shfl(z, 63, 64);
}

// b^(4*lane) via bitwise product decomposition.
__device__ __forceinline__ float pow4lane(float b4, int lane) {
  float m = b4, pw = 1.0f;
#pragma unroll
  for (int i = 0; i < 6; ++i) {
    if (lane & (1 << i)) pw *= m;
    m = m * m;
  }
  return pw;
}

__global__ __launch_bounds__(kWPB * 64, 4)
void macd_kernel(const float* __restrict__ x,
                 const int* __restrict__ p_short,
                 const int* __restrict__ p_long,
                 const int* __restrict__ p_sig,
                 float* __restrict__ out) {
  const int lane = threadIdx.x & 63;
  const int wid  = (blockIdx.x * blockDim.x + threadIdx.x) >> 6;
  const int row  = wid >> 4;            // wid / kSegsPerRow
  const int seg  = wid & (kSegsPerRow - 1);
  const int p0   = seg * kSeg - kChunk; // -256 for seg 0

  const float a_s = 2.0f / (float)(p_short[0] + 1), b_s = 1.0f - a_s;
  const float a_l = 2.0f / (float)(p_long[0]  + 1), b_l = 1.0f - a_l;
  const float a_g = 2.0f / (float)(p_sig[0]   + 1), b_g = 1.0f - a_g;
  const float b2_s = b_s * b_s, b3_s = b2_s * b_s, b4_s = b2_s * b2_s;
  const float b2_l = b_l * b_l, b3_l = b2_l * b_l, b4_l = b2_l * b2_l;
  const float b2_g = b_g * b_g, b3_g = b2_g * b_g, b4_g = b2_g * b2_g;
  // partial-fraction coefficients: signal = c_s*S + c_l*L + c_g*G
  const float c_s =  a_g * b_s / (b_s - b_g);
  const float c_l = -a_g * b_l / (b_l - b_g);
  const float c_g =  b_g * (a_s / (b_g - b_s) - a_l / (b_g - b_l));
  const float pw_s = pow4lane(b4_s, lane);
  const float pw_l = pow4lane(b4_l, lane);
  const float pw_g = pow4lane(b4_g, lane);

  const float* xr = x + row * kT;

  // ---- coalesced loads, all 5 chunks in flight ----
  float4 xq[kChunks];
  if (p0 >= 0) {
#pragma unroll
    for (int k = 0; k < kChunks; ++k)
      xq[k] = *(const float4*)(xr + p0 + k * kChunk + lane * 4);
  } else {  // seg 0: chunk 0 is entirely pre-series -> x0 repeated
    const float x0v = xr[0];
    xq[0] = make_float4(x0v, x0v, x0v, x0v);
#pragma unroll
    for (int k = 1; k < kChunks; ++k)
      xq[k] = *(const float4*)(xr + p0 + k * kChunk + lane * 4);
  }
  // carry into chunk 0 (all three EMAs): first element of the span (exact
  // for seg 0; truncated-history approx otherwise, attenuated by b^256)
  const float xfirst = __shfl(xq[0].x, 0, 64);

  float* om = out + row * kT;
  float* og = om + kB * kT;
  float* oh = og + kB * kT;

  float Cs = xfirst, Cl = xfirst, Cg = xfirst;

#pragma unroll
  for (int k = 0; k < kChunks; ++k) {
    const float4 xv = xq[k];
    // local (per-lane) scans for the three independent EMAs of x
    float s0 = a_s * xv.x;
    float s1 = fmaf(b_s, s0, a_s * xv.y);
    float s2 = fmaf(b_s, s1, a_s * xv.z);
    float s3 = fmaf(b_s, s2, a_s * xv.w);
    float l0 = a_l * xv.x;
    float l1 = fmaf(b_l, l0, a_l * xv.y);
    float l2 = fmaf(b_l, l1, a_l * xv.z);
    float l3 = fmaf(b_l, l2, a_l * xv.w);
    float g0 = a_g * xv.x;
    float g1 = fmaf(b_g, g0, a_g * xv.y);
    float g2 = fmaf(b_g, g1, a_g * xv.z);
    float g3 = fmaf(b_g, g2, a_g * xv.w);

    float exs, Ts, exl, Tl, exg, Tg;
    wave_scan<4>(s3, b4_s, lane, exs, Ts);
    wave_scan<5>(l3, b4_l, lane, exl, Tl);
    wave_scan<4>(g3, b4_g, lane, exg, Tg);

    if (k > 0) {  // chunk 0 is warm-up: only its totals are consumed
      const float cin_s = fmaf(pw_s, Cs, exs);
      const float cin_l = fmaf(pw_l, Cl, exl);
      const float cin_g = fmaf(pw_g, Cg, exg);
      const float S0 = fmaf(b_s,  cin_s, s0);
      const float S1 = fmaf(b2_s, cin_s, s1);
      const float S2 = fmaf(b3_s, cin_s, s2);
      const float S3 = fmaf(b4_s, cin_s, s3);
      const float L0 = fmaf(b_l,  cin_l, l0);
      const float L1 = fmaf(b2_l, cin_l, l1);
      const float L2 = fmaf(b3_l, cin_l, l2);
      const float L3 = fmaf(b4_l, cin_l, l3);
      const float G0 = fmaf(b_g,  cin_g, g0);
      const float G1 = fmaf(b2_g, cin_g, g1);
      const float G2 = fmaf(b3_g, cin_g, g2);
      const float G3 = fmaf(b4_g, cin_g, g3);

      float4 mv, sv, hv;
      mv.x = S0 - L0; mv.y = S1 - L1; mv.z = S2 - L2; mv.w = S3 - L3;
      sv.x = fmaf(c_g, G0, fmaf(c_l, L0, c_s * S0));
      sv.y = fmaf(c_g, G1, fmaf(c_l, L1, c_s * S1));
      sv.z = fmaf(c_g, G2, fmaf(c_l, L2, c_s * S2));
      sv.w = fmaf(c_g, G3, fmaf(c_l, L3, c_s * S3));
      hv.x = mv.x - sv.x; hv.y = mv.y - sv.y;
      hv.z = mv.z - sv.z; hv.w = mv.w - sv.w;

      const int pos = p0 + k * kChunk + lane * 4;
      *(float4*)(om + pos) = mv;
      *(float4*)(og + pos) = sv;
      *(float4*)(oh + pos) = hv;
    }
    Cs = Ts; Cl = Tl; Cg = Tg;
  }
}

extern "C" void kernel_launch(void* const* d_in, const int* in_sizes, int n_in,
                              void* d_out, int out_size, void* d_ws, size_t ws_size,
                              hipStream_t stream) {
  const float* x = (const float*)d_in[0];
  const int* ps  = (const int*)d_in[1];
  const int* pl  = (const int*)d_in[2];
  const int* pg  = (const int*)d_in[3];
  float* out     = (float*)d_out;

  const int total_waves = kB * kSegsPerRow;        // 8192
  const int blocks = total_waves / kWPB;           // 2048
  macd_kernel<<<blocks, kWPB * 64, 0, stream>>>(x, ps, pl, pg, out);
}